// Round 4
// baseline (917.967 us; speedup 1.0000x reference)
//
#include <hip/hip_runtime.h>
#include <hip/hip_bf16.h>

#define SQL  2048
#define SKVL 4096
#define DIML 1024

typedef __attribute__((ext_vector_type(8))) short short8;
typedef __attribute__((ext_vector_type(4))) short short4v;
typedef __attribute__((ext_vector_type(4))) float f32x4;

#define LOG2E 1.4426950408889634f

__device__ __forceinline__ short f2s(float f) {
  return __builtin_bit_cast(short, __float2bfloat16(f));
}
__device__ __forceinline__ float s2f(short s) {
  return __bfloat162float(__builtin_bit_cast(__hip_bfloat16, s));
}

// swizzled LDS address for 128-byte-stride rows
__device__ __forceinline__ char* swz_addr(char* base, int row, int colByte) {
  return base + (row * 128 + (colByte ^ ((row & 7) << 4)));
}

// ---------------- x (f32) -> bf16 ----------------
__global__ __launch_bounds__(256) void convert_x_kernel(
    const float* __restrict__ x, short* __restrict__ xbf)
{
  const size_t i = ((size_t)blockIdx.x * 256 + threadIdx.x) * 8;
  float4 a = *(const float4*)&x[i];
  float4 b = *(const float4*)&x[i + 4];
  short8 o;
  o[0] = f2s(a.x); o[1] = f2s(a.y); o[2] = f2s(a.z); o[3] = f2s(a.w);
  o[4] = f2s(b.x); o[5] = f2s(b.y); o[6] = f2s(b.z); o[7] = f2s(b.w);
  *(short8*)&xbf[i] = o;
}

// ---------------- weight transpose+convert: WT[n][k] = bf16(W[k][n]) ----------------
__global__ __launch_bounds__(256) void transpose_w_kernel(
    const float* __restrict__ W0, const float* __restrict__ W1,
    const float* __restrict__ W2, const float* __restrict__ W3,
    short* __restrict__ WT)
{
  __shared__ float T[64][65];
  const int bid = blockIdx.x;
  const int w = bid >> 8;
  const float* W = (w == 0) ? W0 : (w == 1) ? W1 : (w == 2) ? W2 : W3;
  short* D = WT + (size_t)w * 1048576;
  const int tile = bid & 255;
  const int r0 = (tile >> 4) * 64;
  const int c0 = (tile & 15) * 64;
  const int t = threadIdx.x;
  const int row = t >> 2;
  const int q = t & 3;
#pragma unroll
  for (int i = 0; i < 4; i++)
    *(float4*)&T[row][q * 16 + i * 4] =
        *(const float4*)&W[(size_t)(r0 + row) * 1024 + c0 + q * 16 + i * 4];
  __syncthreads();
  short8 o0, o1;
#pragma unroll
  for (int j = 0; j < 8; j++) {
    o0[j] = f2s(T[q * 16 + j][row]);
    o1[j] = f2s(T[q * 16 + 8 + j][row]);
  }
  *(short8*)&D[(size_t)(c0 + row) * 1024 + r0 + q * 16] = o0;
  *(short8*)&D[(size_t)(c0 + row) * 1024 + r0 + q * 16 + 8] = o1;
}

// ---------------- copy caches into d_out (f32) + K cache rows into Kbf (bf16) ----------------
__global__ __launch_bounds__(256) void copy_cache_kernel(
    const float* __restrict__ kc, const float* __restrict__ vc,
    float* __restrict__ out, short* __restrict__ Kbf)
{
  const int idx = blockIdx.x * 256 + threadIdx.x;
  const int tensor = idx >> 19;
  const int cc = idx & 524287;
  const size_t e = (size_t)cc * 8;
  const int b = (int)(e >> 21);
  const size_t rem = e & 2097151;
  const float* src = tensor ? vc : kc;
  float* dst = out + (tensor ? 12582912u : 4194304u) + (size_t)b * 4194304u + rem;
  float4 a = *(const float4*)&src[e];
  float4 bb = *(const float4*)&src[e + 4];
  *(float4*)dst = a;
  *(float4*)(dst + 4) = bb;
  if (tensor == 0) {
    short8 o;
    o[0] = f2s(a.x); o[1] = f2s(a.y); o[2] = f2s(a.z); o[3] = f2s(a.w);
    o[4] = f2s(bb.x); o[5] = f2s(bb.y); o[6] = f2s(bb.z); o[7] = f2s(bb.w);
    *(short8*)&Kbf[(size_t)b * 4194304u + rem] = o;
  }
}

// ---------------- mask (f32 [B][SQ][SKV]) -> maskT bf16 [B][SKV][SQ], *(-10000*log2e) ----------------
__global__ __launch_bounds__(256) void transpose_mask_kernel(
    const float* __restrict__ mask, short* __restrict__ maskT)
{
  __shared__ float T[64][65];
  const int bid = blockIdx.x;          // b(2) x qt(32) x kt(64)
  const int ktile = bid & 63;
  const int qtile = (bid >> 6) & 31;
  const int b = bid >> 11;
  const int q0 = qtile * 64, k0 = ktile * 64;
  const int t = threadIdx.x;
  const int row = t >> 2;
  const int q4 = t & 3;
  const float* src = mask + (size_t)(b * SQL + q0 + row) * SKVL + k0 + q4 * 16;
#pragma unroll
  for (int i = 0; i < 4; i++)
    *(float4*)&T[row][q4 * 16 + i * 4] = *(const float4*)&src[i * 4];
  __syncthreads();
  const float MS = -10000.0f * LOG2E;
  short8 o0, o1;
#pragma unroll
  for (int j = 0; j < 8; j++) {
    o0[j] = f2s(T[q4 * 16 + j][row] * MS);
    o1[j] = f2s(T[q4 * 16 + 8 + j][row] * MS);
  }
  short* D = maskT + (size_t)b * SKVL * SQL + (size_t)(k0 + row) * SQL + q0 + q4 * 16;
  *(short8*)&D[0] = o0;
  *(short8*)&D[8] = o1;
}

// ---------------- GEMM: C = A(bf16)[4096,1024] * BT^T + bias(f32) ----------------
__global__ __launch_bounds__(256) void gemm_bt_bias(
    const short* __restrict__ A,
    const short* __restrict__ BT,
    const float* __restrict__ bias,
    float* __restrict__ Cf,
    short* __restrict__ Cb,
    int dst_batch_rows, int dst_row0, float oscale)
{
  constexpr int K = 1024;
  __shared__ __align__(16) short As[128 * 32];
  __shared__ __align__(16) short Bs[128 * 32];
  const int tid = threadIdx.x;
  const int lane = tid & 63;
  const int wave = tid >> 6;
  const int bid = blockIdx.x;
  const int nb = bid & 7;
  const int mb = bid >> 3;
  const int wm = wave >> 1;
  const int wn = wave & 1;
  const int g = lane >> 4;
  const int fr = lane & 15;

  f32x4 acc[4][4] = {};

  const int c0 = tid, c1 = tid + 256;
  const short* Ab0 = A + (size_t)(mb * 128 + (c0 >> 2)) * K + (c0 & 3) * 8;
  const short* Ab1 = A + (size_t)(mb * 128 + (c1 >> 2)) * K + (c1 & 3) * 8;
  const short* Bb0 = BT + (size_t)(nb * 128 + (c0 >> 2)) * K + (c0 & 3) * 8;
  const short* Bb1 = BT + (size_t)(nb * 128 + (c1 >> 2)) * K + (c1 & 3) * 8;

  for (int k0 = 0; k0 < K; k0 += 32) {
    __syncthreads();
    *(short8*)&As[c0 * 8] = *(const short8*)&Ab0[k0];
    *(short8*)&As[c1 * 8] = *(const short8*)&Ab1[k0];
    *(short8*)&Bs[c0 * 8] = *(const short8*)&Bb0[k0];
    *(short8*)&Bs[c1 * 8] = *(const short8*)&Bb1[k0];
    __syncthreads();
    short8 af[4], bfv[4];
#pragma unroll
    for (int m = 0; m < 4; m++)
      af[m] = *(const short8*)&As[(wm * 64 + m * 16 + fr) * 32 + g * 8];
#pragma unroll
    for (int n = 0; n < 4; n++)
      bfv[n] = *(const short8*)&Bs[(wn * 64 + n * 16 + fr) * 32 + g * 8];
#pragma unroll
    for (int m = 0; m < 4; m++)
#pragma unroll
      for (int n = 0; n < 4; n++)
        acc[m][n] = __builtin_amdgcn_mfma_f32_16x16x32_bf16(af[m], bfv[n], acc[m][n], 0, 0, 0);
  }

  const int gm = mb * 128 + wm * 64;
  const int gn = nb * 128 + wn * 64;
  float bv[4];
#pragma unroll
  for (int n = 0; n < 4; n++) bv[n] = bias[gn + n * 16 + fr];
#pragma unroll
  for (int m = 0; m < 4; m++) {
#pragma unroll
    for (int r = 0; r < 4; r++) {
      const int row = gm + m * 16 + g * 4 + r;
      const int drow = (row >> 11) * dst_batch_rows + dst_row0 + (row & 2047);
      float vals[4];
#pragma unroll
      for (int n = 0; n < 4; n++) vals[n] = (acc[m][n][r] + bv[n]) * oscale;
      if (Cf) {
#pragma unroll
        for (int n = 0; n < 4; n++)
          Cf[(size_t)drow * 1024 + gn + n * 16 + fr] = vals[n];
      }
      if (Cb) {
#pragma unroll
        for (int n = 0; n < 4; n++)
          Cb[(size_t)drow * 1024 + gn + n * 16 + fr] = f2s(vals[n]);
      }
    }
  }
}

// ---------------- V (f32, d_out region) -> VT bf16 [B*H][64][SKVL] ----------------
__global__ __launch_bounds__(256) void transpose_v_kernel(
    const float* __restrict__ Vf, short* __restrict__ VT)
{
  __shared__ float T[64][65];
  const int bid = blockIdx.x;      // b(2) x h(16) x kb(64)
  const int kb = bid & 63;
  const int h = (bid >> 6) & 15;
  const int b = bid >> 10;
  const int kt = kb * 64;
  const int t = threadIdx.x;
  const int row = t >> 2;
  const int q = t & 3;
  const float* src = Vf + (size_t)(b * SKVL + kt + row) * DIML + h * 64 + q * 16;
#pragma unroll
  for (int i = 0; i < 4; i++)
    *(float4*)&T[row][q * 16 + i * 4] = *(const float4*)&src[i * 4];
  __syncthreads();
  short8 o0, o1;
#pragma unroll
  for (int j = 0; j < 8; j++) {
    o0[j] = f2s(T[q * 16 + j][row]);
    o1[j] = f2s(T[q * 16 + 8 + j][row]);
  }
  short* D = VT + (size_t)((b * 16 + h) * 64 + row) * SKVL + kt;
  *(short8*)&D[q * 16] = o0;
  *(short8*)&D[q * 16 + 8] = o1;
}

// ---------------- flash attention, KV-split x2: 4 waves x 16 q-rows, KVBLK=64 ----------------
// Q bf16 (pre-scaled by 0.125*log2e); K bf16; VT bf16 [B*H][64][SKVL];
// maskT bf16 [B][SKV][SQ] pre-scaled by -10000*log2e. Outputs unnormalized
// partial ctx (bf16) + per-row (m, l) in log2 domain.
__global__ __launch_bounds__(256, 8) void attn_kernel(
    const short* __restrict__ Q,
    const short* __restrict__ Kb_,
    const short* __restrict__ VT_,
    const short* __restrict__ maskT,
    short* __restrict__ pctx,
    float2* __restrict__ ml)
{
  __shared__ __align__(16) char Pl[4][16 * 128];
  const int tid = threadIdx.x;
  const int lane = tid & 63;
  const int wave = tid >> 6;
  const int bid = blockIdx.x;
  const int qb = bid & 31;
  const int bh = (bid >> 5) & 31;
  const int half = bid >> 10;
  const int b = bh >> 4;
  const int h = bh & 15;
  const int q0 = qb * 64 + wave * 16;
  const int g = lane >> 4;
  const int c = lane & 15;
  char* PlW = Pl[wave];

  short8 qf[2];
  {
    const short* qp = Q + (size_t)(b * SQL + q0 + c) * DIML + h * 64 + g * 8;
    qf[0] = *(const short8*)qp;
    qf[1] = *(const short8*)(qp + 32);
  }

  float m_run[4] = {-1e30f, -1e30f, -1e30f, -1e30f};
  float lpart[4] = {0.f, 0.f, 0.f, 0.f};
  f32x4 ctxa[4] = {};

  const short* Kp = Kb_ + (size_t)b * SKVL * DIML + h * 64;
  const short* Vp = VT_ + (size_t)(b * 16 + h) * 64 * SKVL;
  const short* Mb = maskT + (size_t)b * SKVL * SQL + q0 + g * 4;

  const int k_beg = half * (SKVL / 2);
  const int k_end = k_beg + SKVL / 2;
  for (int kt = k_beg; kt < k_end; kt += 64) {
    // QK^T (scores already in log2 domain via Q prescale)
    f32x4 s[4] = {};
#pragma unroll
    for (int n = 0; n < 4; n++) {
      const short* kp = Kp + (size_t)(kt + n * 16 + c) * DIML + g * 8;
      short8 k0 = *(const short8*)kp;
      short8 k1 = *(const short8*)(kp + 32);
      s[n] = __builtin_amdgcn_mfma_f32_16x16x32_bf16(qf[0], k0, s[n], 0, 0, 0);
      s[n] = __builtin_amdgcn_mfma_f32_16x16x32_bf16(qf[1], k1, s[n], 0, 0, 0);
    }
    // additive mask bias, transposed layout: 4x 8B loads
#pragma unroll
    for (int n = 0; n < 4; n++) {
      short4v mv = *(const short4v*)&Mb[(size_t)(kt + n * 16 + c) * SQL];
#pragma unroll
      for (int r = 0; r < 4; r++) s[n][r] += s2f(mv[r]);
    }
    // defer-max (log2 domain, threshold 11.5 ~ 8 nats)
    float mloc[4];
#pragma unroll
    for (int r = 0; r < 4; r++)
      mloc[r] = fmaxf(fmaxf(s[0][r], s[1][r]), fmaxf(s[2][r], s[3][r]));
    const int grow = (mloc[0] > m_run[0] + 11.5f) || (mloc[1] > m_run[1] + 11.5f) ||
                     (mloc[2] > m_run[2] + 11.5f) || (mloc[3] > m_run[3] + 11.5f);
    if (__any(grow)) {
#pragma unroll
      for (int r = 0; r < 4; r++) {
        float mt = mloc[r];
#pragma unroll
        for (int off = 1; off < 16; off <<= 1) mt = fmaxf(mt, __shfl_xor(mt, off));
        const float mnew = fmaxf(m_run[r], mt);
        const float sc = exp2f(m_run[r] - mnew);
        m_run[r] = mnew;
        lpart[r] *= sc;
        ctxa[0][r] *= sc; ctxa[1][r] *= sc; ctxa[2][r] *= sc; ctxa[3][r] *= sc;
      }
    }
    // exp2 + per-lane partial sum + pack P into wave-private LDS
#pragma unroll
    for (int r = 0; r < 4; r++) {
#pragma unroll
      for (int n = 0; n < 4; n++) {
        float p = exp2f(s[n][r] - m_run[r]);
        lpart[r] += p;
        *(short*)swz_addr(PlW, g * 4 + r, (n * 16 + c) * 2) = f2s(p);
      }
    }
    // PV
#pragma unroll
    for (int ks = 0; ks < 2; ks++) {
      short8 pa = *(short8*)swz_addr(PlW, c, ks * 64 + g * 16);
#pragma unroll
      for (int n = 0; n < 4; n++) {
        short8 vt = *(const short8*)&Vp[(size_t)(n * 16 + c) * SKVL + kt + ks * 32 + g * 8];
        ctxa[n] = __builtin_amdgcn_mfma_f32_16x16x32_bf16(pa, vt, ctxa[n], 0, 0, 0);
      }
    }
  }

  // epilogue: reduce l across the 16-lane group, store partials
#pragma unroll
  for (int r = 0; r < 4; r++) {
    float l = lpart[r];
#pragma unroll
    for (int off = 1; off < 16; off <<= 1) l += __shfl_xor(l, off);
    const int rg = ((b * 16 + h) << 11) + q0 + g * 4 + r;
    const size_t base = ((size_t)half << 22) + (size_t)rg * 64;
#pragma unroll
    for (int n = 0; n < 4; n++)
      pctx[base + n * 16 + c] = f2s(ctxa[n][r]);
    if (c == 0) ml[half * 65536 + rg] = make_float2(m_run[r], l);
  }
}

// ---------------- combine two KV-halves -> ctx bf16 [B*SQ][DIM] ----------------
__global__ __launch_bounds__(256) void combine_kernel(
    const short* __restrict__ pctx, const float2* __restrict__ ml,
    short* __restrict__ ctxb)
{
  const int t = blockIdx.x * 256 + threadIdx.x;   // 262144
  const int r = t >> 2;
  const int seg = (t & 3) * 16;
  const float2 ml0 = ml[r];
  const float2 ml1 = ml[65536 + r];
  const float m = fmaxf(ml0.x, ml1.x);
  const float w0 = exp2f(ml0.x - m);
  const float w1 = exp2f(ml1.x - m);
  const float inv = 1.0f / (ml0.y * w0 + ml1.y * w1);
  const short8 a0 = *(const short8*)&pctx[(size_t)r * 64 + seg];
  const short8 a1 = *(const short8*)&pctx[(size_t)r * 64 + seg + 8];
  const short8 b0 = *(const short8*)&pctx[(1ull << 22) + (size_t)r * 64 + seg];
  const short8 b1 = *(const short8*)&pctx[(1ull << 22) + (size_t)r * 64 + seg + 8];
  short8 o0, o1;
#pragma unroll
  for (int j = 0; j < 8; j++) {
    o0[j] = f2s((s2f(a0[j]) * w0 + s2f(b0[j]) * w1) * inv);
    o1[j] = f2s((s2f(a1[j]) * w0 + s2f(b1[j]) * w1) * inv);
  }
  const int b = r >> 15;
  const int h = (r >> 11) & 15;
  const int q = r & 2047;
  short* D = ctxb + (size_t)(b * 2048 + q) * 1024 + h * 64 + seg;
  *(short8*)&D[0] = o0;
  *(short8*)&D[8] = o1;
}

extern "C" void kernel_launch(void* const* d_in, const int* in_sizes, int n_in,
                              void* d_out, int out_size, void* d_ws, size_t ws_size,
                              hipStream_t stream)
{
  const float* x   = (const float*)d_in[0];
  const float* kc  = (const float*)d_in[1];
  const float* vc  = (const float*)d_in[2];
  const float* msk = (const float*)d_in[3];
  const float* Wq  = (const float*)d_in[4];
  const float* bq  = (const float*)d_in[5];
  const float* Wk  = (const float*)d_in[6];
  const float* bk  = (const float*)d_in[7];
  const float* Wv  = (const float*)d_in[8];
  const float* bv  = (const float*)d_in[9];
  const float* Wo  = (const float*)d_in[10];
  const float* bo  = (const float*)d_in[11];

  float* outf = (float*)d_out;
  float* kout = outf + 4194304;
  float* vout = outf + 12582912;

  short* ws_s  = (short*)d_ws;
  short* WT    = ws_s;                            // 8 MB
  short* xbf   = ws_s + (size_t)4 * 1048576;      // 8 MB (reused as ctx)
  short* qbf   = ws_s + (size_t)8 * 1048576;      // 8 MB
  short* Kbf   = ws_s + (size_t)12 * 1048576;     // 16 MB
  short* VTb   = ws_s + (size_t)20 * 1048576;     // 16 MB
  short* maskT = ws_s + (size_t)28 * 1048576;     // 32 MB
  short* pctx  = ws_s + (size_t)44 * 1048576;     // 16 MB
  float2* mlp  = (float2*)(ws_s + (size_t)52 * 1048576);  // 1 MB
  short* ctxb  = xbf;

  const float qscale = 0.125f * LOG2E;

  convert_x_kernel<<<2048, 256, 0, stream>>>(x, xbf);
  transpose_w_kernel<<<1024, 256, 0, stream>>>(Wq, Wk, Wv, Wo, WT);
  copy_cache_kernel<<<4096, 256, 0, stream>>>(kc, vc, outf, Kbf);
  transpose_mask_kernel<<<4096, 256, 0, stream>>>(msk, maskT);
  gemm_bt_bias<<<256, 256, 0, stream>>>(xbf, WT,               bq, nullptr, qbf, 2048, 0, qscale);
  gemm_bt_bias<<<256, 256, 0, stream>>>(xbf, WT + 1048576,     bk, kout, Kbf,   4096, 2048, 1.0f);
  gemm_bt_bias<<<256, 256, 0, stream>>>(xbf, WT + 2 * 1048576, bv, vout, nullptr, 4096, 2048, 1.0f);
  transpose_v_kernel<<<2048, 256, 0, stream>>>(vout, VTb);
  attn_kernel<<<2048, 256, 0, stream>>>(qbf, Kbf, VTb, maskT, pctx, mlp);
  combine_kernel<<<1024, 256, 0, stream>>>(pctx, mlp, ctxb);
  gemm_bt_bias<<<256, 256, 0, stream>>>(ctxb, WT + 3 * 1048576, bo, outf, nullptr, 2048, 0, 1.0f);
}

// Round 5
// 658.837 us; speedup vs baseline: 1.3933x; 1.3933x over previous
//
#include <hip/hip_runtime.h>
#include <hip/hip_bf16.h>

#define SQL  2048
#define SKVL 4096
#define DIML 1024

typedef __attribute__((ext_vector_type(8))) short short8;
typedef __attribute__((ext_vector_type(4))) float f32x4;

#define LOG2E 1.4426950408889634f
#define MBIGC (10000.0f * LOG2E)

__device__ __forceinline__ short f2s(float f) {
  return __builtin_bit_cast(short, __float2bfloat16(f));
}
__device__ __forceinline__ float s2f(short s) {
  return __bfloat162float(__builtin_bit_cast(__hip_bfloat16, s));
}

// swizzled LDS address for 128-byte-stride rows
__device__ __forceinline__ char* swz_addr(char* base, int row, int colByte) {
  return base + (row * 128 + (colByte ^ ((row & 7) << 4)));
}

// ---------------- x (f32) -> bf16 ----------------
__global__ __launch_bounds__(256) void convert_x_kernel(
    const float* __restrict__ x, short* __restrict__ xbf)
{
  const size_t i = ((size_t)blockIdx.x * 256 + threadIdx.x) * 8;
  float4 a = *(const float4*)&x[i];
  float4 b = *(const float4*)&x[i + 4];
  short8 o;
  o[0] = f2s(a.x); o[1] = f2s(a.y); o[2] = f2s(a.z); o[3] = f2s(a.w);
  o[4] = f2s(b.x); o[5] = f2s(b.y); o[6] = f2s(b.z); o[7] = f2s(b.w);
  *(short8*)&xbf[i] = o;
}

// ---------------- weight transpose+convert: WT[n][k] = bf16(W[k][n]) ----------------
__global__ __launch_bounds__(256) void transpose_w_kernel(
    const float* __restrict__ W0, const float* __restrict__ W1,
    const float* __restrict__ W2, const float* __restrict__ W3,
    short* __restrict__ WT)
{
  __shared__ float T[64][65];
  const int bid = blockIdx.x;
  const int w = bid >> 8;
  const float* W = (w == 0) ? W0 : (w == 1) ? W1 : (w == 2) ? W2 : W3;
  short* D = WT + (size_t)w * 1048576;
  const int tile = bid & 255;
  const int r0 = (tile >> 4) * 64;
  const int c0 = (tile & 15) * 64;
  const int t = threadIdx.x;
  const int row = t >> 2;
  const int q = t & 3;
#pragma unroll
  for (int i = 0; i < 4; i++)
    *(float4*)&T[row][q * 16 + i * 4] =
        *(const float4*)&W[(size_t)(r0 + row) * 1024 + c0 + q * 16 + i * 4];
  __syncthreads();
  short8 o0, o1;
#pragma unroll
  for (int j = 0; j < 8; j++) {
    o0[j] = f2s(T[q * 16 + j][row]);
    o1[j] = f2s(T[q * 16 + 8 + j][row]);
  }
  *(short8*)&D[(size_t)(c0 + row) * 1024 + r0 + q * 16] = o0;
  *(short8*)&D[(size_t)(c0 + row) * 1024 + r0 + q * 16 + 8] = o1;
}

// ---------------- copy caches into d_out (f32) + K cache rows into Kbf (bf16) ----------------
__global__ __launch_bounds__(256) void copy_cache_kernel(
    const float* __restrict__ kc, const float* __restrict__ vc,
    float* __restrict__ out, short* __restrict__ Kbf)
{
  const int idx = blockIdx.x * 256 + threadIdx.x;
  const int tensor = idx >> 19;
  const int cc = idx & 524287;
  const size_t e = (size_t)cc * 8;
  const int b = (int)(e >> 21);
  const size_t rem = e & 2097151;
  const float* src = tensor ? vc : kc;
  float* dst = out + (tensor ? 12582912u : 4194304u) + (size_t)b * 4194304u + rem;
  float4 a = *(const float4*)&src[e];
  float4 bb = *(const float4*)&src[e + 4];
  *(float4*)dst = a;
  *(float4*)(dst + 4) = bb;
  if (tensor == 0) {
    short8 o;
    o[0] = f2s(a.x); o[1] = f2s(a.y); o[2] = f2s(a.z); o[3] = f2s(a.w);
    o[4] = f2s(bb.x); o[5] = f2s(bb.y); o[6] = f2s(bb.z); o[7] = f2s(bb.w);
    *(short8*)&Kbf[(size_t)b * 4194304u + rem] = o;
  }
}

// ---------------- mask (f32 [B][SQ][SKV]) -> bit-packed maskW [B][32 qb][SKV] uint64 ----------------
// word bit j = mask[b][qb*64+j][kv] > 0.5
__global__ __launch_bounds__(256) void pack_mask_kernel(
    const float* __restrict__ mask, unsigned long long* __restrict__ maskW)
{
  __shared__ float T[64][65];
  const int bid = blockIdx.x;          // b(2) x qt(32) x kt(64)
  const int ktile = bid & 63;
  const int qtile = (bid >> 6) & 31;
  const int b = bid >> 11;
  const int q0 = qtile * 64, k0 = ktile * 64;
  const int t = threadIdx.x;
  const int row = t >> 2;
  const int q4 = t & 3;
  const float* src = mask + (size_t)(b * SQL + q0 + row) * SKVL + k0 + q4 * 16;
#pragma unroll
  for (int i = 0; i < 4; i++)
    *(float4*)&T[row][q4 * 16 + i * 4] = *(const float4*)&src[i * 4];
  __syncthreads();
  const int wv = t >> 6, ln = t & 63;
#pragma unroll
  for (int j = 0; j < 16; j++) {
    const int kv = wv * 16 + j;
    unsigned long long w = __ballot(T[ln][kv] > 0.5f);   // bit ln = q0+ln masked
    if (ln == 0)
      maskW[((size_t)(b * 32 + qtile)) * SKVL + k0 + kv] = w;
  }
}

// ---------------- GEMM: C = A(bf16)[4096,1024] * BT^T + bias(f32) ----------------
__global__ __launch_bounds__(256) void gemm_bt_bias(
    const short* __restrict__ A,
    const short* __restrict__ BT,
    const float* __restrict__ bias,
    float* __restrict__ Cf,
    short* __restrict__ Cb,
    int dst_batch_rows, int dst_row0, float oscale)
{
  constexpr int K = 1024;
  __shared__ __align__(16) short As[128 * 32];
  __shared__ __align__(16) short Bs[128 * 32];
  const int tid = threadIdx.x;
  const int lane = tid & 63;
  const int wave = tid >> 6;
  const int bid = blockIdx.x;
  const int nb = bid & 7;
  const int mb = bid >> 3;
  const int wm = wave >> 1;
  const int wn = wave & 1;
  const int g = lane >> 4;
  const int fr = lane & 15;

  f32x4 acc[4][4] = {};

  const int c0 = tid, c1 = tid + 256;
  const short* Ab0 = A + (size_t)(mb * 128 + (c0 >> 2)) * K + (c0 & 3) * 8;
  const short* Ab1 = A + (size_t)(mb * 128 + (c1 >> 2)) * K + (c1 & 3) * 8;
  const short* Bb0 = BT + (size_t)(nb * 128 + (c0 >> 2)) * K + (c0 & 3) * 8;
  const short* Bb1 = BT + (size_t)(nb * 128 + (c1 >> 2)) * K + (c1 & 3) * 8;

  for (int k0 = 0; k0 < K; k0 += 32) {
    __syncthreads();
    *(short8*)&As[c0 * 8] = *(const short8*)&Ab0[k0];
    *(short8*)&As[c1 * 8] = *(const short8*)&Ab1[k0];
    *(short8*)&Bs[c0 * 8] = *(const short8*)&Bb0[k0];
    *(short8*)&Bs[c1 * 8] = *(const short8*)&Bb1[k0];
    __syncthreads();
    short8 af[4], bfv[4];
#pragma unroll
    for (int m = 0; m < 4; m++)
      af[m] = *(const short8*)&As[(wm * 64 + m * 16 + fr) * 32 + g * 8];
#pragma unroll
    for (int n = 0; n < 4; n++)
      bfv[n] = *(const short8*)&Bs[(wn * 64 + n * 16 + fr) * 32 + g * 8];
#pragma unroll
    for (int m = 0; m < 4; m++)
#pragma unroll
      for (int n = 0; n < 4; n++)
        acc[m][n] = __builtin_amdgcn_mfma_f32_16x16x32_bf16(af[m], bfv[n], acc[m][n], 0, 0, 0);
  }

  const int gm = mb * 128 + wm * 64;
  const int gn = nb * 128 + wn * 64;
  float bv[4];
#pragma unroll
  for (int n = 0; n < 4; n++) bv[n] = bias[gn + n * 16 + fr];
#pragma unroll
  for (int m = 0; m < 4; m++) {
#pragma unroll
    for (int r = 0; r < 4; r++) {
      const int row = gm + m * 16 + g * 4 + r;
      const int drow = (row >> 11) * dst_batch_rows + dst_row0 + (row & 2047);
      float vals[4];
#pragma unroll
      for (int n = 0; n < 4; n++) vals[n] = (acc[m][n][r] + bv[n]) * oscale;
      if (Cf) {
#pragma unroll
        for (int n = 0; n < 4; n++)
          Cf[(size_t)drow * 1024 + gn + n * 16 + fr] = vals[n];
      }
      if (Cb) {
#pragma unroll
        for (int n = 0; n < 4; n++)
          Cb[(size_t)drow * 1024 + gn + n * 16 + fr] = f2s(vals[n]);
      }
    }
  }
}

// ---------------- V (f32, d_out region) -> VT bf16 [B*H][64][SKVL] ----------------
__global__ __launch_bounds__(256) void transpose_v_kernel(
    const float* __restrict__ Vf, short* __restrict__ VT)
{
  __shared__ float T[64][65];
  const int bid = blockIdx.x;      // b(2) x h(16) x kb(64)
  const int kb = bid & 63;
  const int h = (bid >> 6) & 15;
  const int b = bid >> 10;
  const int kt = kb * 64;
  const int t = threadIdx.x;
  const int row = t >> 2;
  const int q = t & 3;
  const float* src = Vf + (size_t)(b * SKVL + kt + row) * DIML + h * 64 + q * 16;
#pragma unroll
  for (int i = 0; i < 4; i++)
    *(float4*)&T[row][q * 16 + i * 4] = *(const float4*)&src[i * 4];
  __syncthreads();
  short8 o0, o1;
#pragma unroll
  for (int j = 0; j < 8; j++) {
    o0[j] = f2s(T[q * 16 + j][row]);
    o1[j] = f2s(T[q * 16 + 8 + j][row]);
  }
  short* D = VT + (size_t)((b * 16 + h) * 64 + row) * SKVL + kt;
  *(short8*)&D[q * 16] = o0;
  *(short8*)&D[q * 16 + 8] = o1;
}

// ---------------- flash attention, KV-split x2, XCD-partitioned swizzle ----------------
// Q bf16 (pre-scaled by 0.125*log2e); K bf16; VT bf16 [B*H][64][SKVL];
// maskW bit-packed [B][32 qb][SKVL] uint64. Outputs unnormalized partial ctx
// (bf16) + per-row (m, l) in log2 domain.
__global__ __launch_bounds__(256) void attn_kernel(
    const short* __restrict__ Q,
    const short* __restrict__ Kb_,
    const short* __restrict__ VT_,
    const unsigned long long* __restrict__ maskW,
    short* __restrict__ pctx,
    float2* __restrict__ ml)
{
  __shared__ __align__(16) char Pl[4][16 * 128];
  const int tid = threadIdx.x;
  const int lane = tid & 63;
  const int wave = tid >> 6;
  // XCD-partitioned bijective swizzle: xcd gets 8 (bh,half) groups x 32 qb
  const int gid = blockIdx.x;          // 0..2047
  const int xcd = gid & 7;
  const int seq = gid >> 3;            // 0..255
  const int group = xcd * 8 + (seq >> 5);  // 0..63
  const int qb = seq & 31;
  const int half = group & 1;
  const int bh = group >> 1;
  const int b = bh >> 4;
  const int h = bh & 15;
  const int q0 = qb * 64 + wave * 16;
  const int g = lane >> 4;
  const int c = lane & 15;
  char* PlW = Pl[wave];

  short8 qf[2];
  {
    const short* qp = Q + (size_t)(b * SQL + q0 + c) * DIML + h * 64 + g * 8;
    qf[0] = *(const short8*)qp;
    qf[1] = *(const short8*)(qp + 32);
  }

  float m_run[4] = {-1e30f, -1e30f, -1e30f, -1e30f};
  float lpart[4] = {0.f, 0.f, 0.f, 0.f};
  f32x4 ctxa[4] = {};

  const short* Kp = Kb_ + (size_t)b * SKVL * DIML + h * 64;
  const short* Vp = VT_ + (size_t)(b * 16 + h) * 64 * SKVL;
  const unsigned long long* Mw = maskW + (size_t)(b * 32 + qb) * SKVL;
  const int mshift = wave * 16 + g * 4;

  const int k_beg = half * (SKVL / 2);
  const int k_end = k_beg + SKVL / 2;
  for (int kt = k_beg; kt < k_end; kt += 64) {
    // QK^T (log2 domain via Q prescale)
    f32x4 s[4] = {};
#pragma unroll
    for (int n = 0; n < 4; n++) {
      const short* kp = Kp + (size_t)(kt + n * 16 + c) * DIML + g * 8;
      short8 k0 = *(const short8*)kp;
      short8 k1 = *(const short8*)(kp + 32);
      s[n] = __builtin_amdgcn_mfma_f32_16x16x32_bf16(qf[0], k0, s[n], 0, 0, 0);
      s[n] = __builtin_amdgcn_mfma_f32_16x16x32_bf16(qf[1], k1, s[n], 0, 0, 0);
    }
    // bit-packed additive mask: one 8B coalesced load per n
#pragma unroll
    for (int n = 0; n < 4; n++) {
      const unsigned bits =
          (unsigned)(Mw[kt + n * 16 + c] >> mshift) & 0xFu;
#pragma unroll
      for (int r = 0; r < 4; r++)
        s[n][r] = fmaf((float)((bits >> r) & 1u), -MBIGC, s[n][r]);
    }
    // defer-max (log2 domain, threshold 11.5 ~ 8 nats)
    float mloc[4];
#pragma unroll
    for (int r = 0; r < 4; r++)
      mloc[r] = fmaxf(fmaxf(s[0][r], s[1][r]), fmaxf(s[2][r], s[3][r]));
    const int grow = (mloc[0] > m_run[0] + 11.5f) || (mloc[1] > m_run[1] + 11.5f) ||
                     (mloc[2] > m_run[2] + 11.5f) || (mloc[3] > m_run[3] + 11.5f);
    if (__any(grow)) {
#pragma unroll
      for (int r = 0; r < 4; r++) {
        float mt = mloc[r];
#pragma unroll
        for (int off = 1; off < 16; off <<= 1) mt = fmaxf(mt, __shfl_xor(mt, off));
        const float mnew = fmaxf(m_run[r], mt);
        const float sc = exp2f(m_run[r] - mnew);
        m_run[r] = mnew;
        lpart[r] *= sc;
        ctxa[0][r] *= sc; ctxa[1][r] *= sc; ctxa[2][r] *= sc; ctxa[3][r] *= sc;
      }
    }
    // exp2 + per-lane partial sum + pack P into wave-private LDS
#pragma unroll
    for (int r = 0; r < 4; r++) {
#pragma unroll
      for (int n = 0; n < 4; n++) {
        float p = exp2f(s[n][r] - m_run[r]);
        lpart[r] += p;
        *(short*)swz_addr(PlW, g * 4 + r, (n * 16 + c) * 2) = f2s(p);
      }
    }
    // PV
#pragma unroll
    for (int ks = 0; ks < 2; ks++) {
      short8 pa = *(short8*)swz_addr(PlW, c, ks * 64 + g * 16);
#pragma unroll
      for (int n = 0; n < 4; n++) {
        short8 vt = *(const short8*)&Vp[(size_t)(n * 16 + c) * SKVL + kt + ks * 32 + g * 8];
        ctxa[n] = __builtin_amdgcn_mfma_f32_16x16x32_bf16(pa, vt, ctxa[n], 0, 0, 0);
      }
    }
  }

  // epilogue: reduce l across the 16-lane group, store partials
#pragma unroll
  for (int r = 0; r < 4; r++) {
    float l = lpart[r];
#pragma unroll
    for (int off = 1; off < 16; off <<= 1) l += __shfl_xor(l, off);
    const int rg = ((b * 16 + h) << 11) + q0 + g * 4 + r;
    const size_t base = ((size_t)half << 22) + (size_t)rg * 64;
#pragma unroll
    for (int n = 0; n < 4; n++)
      pctx[base + n * 16 + c] = f2s(ctxa[n][r]);
    if (c == 0) ml[half * 65536 + rg] = make_float2(m_run[r], l);
  }
}

// ---------------- combine two KV-halves -> ctx bf16 [B*SQ][DIM] ----------------
__global__ __launch_bounds__(256) void combine_kernel(
    const short* __restrict__ pctx, const float2* __restrict__ ml,
    short* __restrict__ ctxb)
{
  const int t = blockIdx.x * 256 + threadIdx.x;   // 262144
  const int r = t >> 2;
  const int seg = (t & 3) * 16;
  const float2 ml0 = ml[r];
  const float2 ml1 = ml[65536 + r];
  const float m = fmaxf(ml0.x, ml1.x);
  const float w0 = exp2f(ml0.x - m);
  const float w1 = exp2f(ml1.x - m);
  const float inv = 1.0f / (ml0.y * w0 + ml1.y * w1);
  const short8 a0 = *(const short8*)&pctx[(size_t)r * 64 + seg];
  const short8 a1 = *(const short8*)&pctx[(size_t)r * 64 + seg + 8];
  const short8 b0 = *(const short8*)&pctx[(1ull << 22) + (size_t)r * 64 + seg];
  const short8 b1 = *(const short8*)&pctx[(1ull << 22) + (size_t)r * 64 + seg + 8];
  short8 o0, o1;
#pragma unroll
  for (int j = 0; j < 8; j++) {
    o0[j] = f2s((s2f(a0[j]) * w0 + s2f(b0[j]) * w1) * inv);
    o1[j] = f2s((s2f(a1[j]) * w0 + s2f(b1[j]) * w1) * inv);
  }
  const int b = r >> 15;
  const int h = (r >> 11) & 15;
  const int q = r & 2047;
  short* D = ctxb + (size_t)(b * 2048 + q) * 1024 + h * 64 + seg;
  *(short8*)&D[0] = o0;
  *(short8*)&D[8] = o1;
}

extern "C" void kernel_launch(void* const* d_in, const int* in_sizes, int n_in,
                              void* d_out, int out_size, void* d_ws, size_t ws_size,
                              hipStream_t stream)
{
  const float* x   = (const float*)d_in[0];
  const float* kc  = (const float*)d_in[1];
  const float* vc  = (const float*)d_in[2];
  const float* msk = (const float*)d_in[3];
  const float* Wq  = (const float*)d_in[4];
  const float* bq  = (const float*)d_in[5];
  const float* Wk  = (const float*)d_in[6];
  const float* bk  = (const float*)d_in[7];
  const float* Wv  = (const float*)d_in[8];
  const float* bv  = (const float*)d_in[9];
  const float* Wo  = (const float*)d_in[10];
  const float* bo  = (const float*)d_in[11];

  float* outf = (float*)d_out;
  float* kout = outf + 4194304;
  float* vout = outf + 12582912;

  short* ws_s  = (short*)d_ws;
  short* WT    = ws_s;                            // 8 MB
  short* xbf   = ws_s + (size_t)4 * 1048576;      // 8 MB (reused as ctx)
  short* qbf   = ws_s + (size_t)8 * 1048576;      // 8 MB
  short* Kbf   = ws_s + (size_t)12 * 1048576;     // 16 MB
  short* VTb   = ws_s + (size_t)20 * 1048576;     // 16 MB
  unsigned long long* maskW = (unsigned long long*)(ws_s + (size_t)28 * 1048576);  // 2 MB
  short* pctx  = ws_s + (size_t)44 * 1048576;     // 16 MB
  float2* mlp  = (float2*)(ws_s + (size_t)52 * 1048576);  // 1 MB
  short* ctxb  = xbf;

  const float qscale = 0.125f * LOG2E;

  convert_x_kernel<<<2048, 256, 0, stream>>>(x, xbf);
  transpose_w_kernel<<<1024, 256, 0, stream>>>(Wq, Wk, Wv, Wo, WT);
  copy_cache_kernel<<<4096, 256, 0, stream>>>(kc, vc, outf, Kbf);
  pack_mask_kernel<<<4096, 256, 0, stream>>>(msk, maskW);
  gemm_bt_bias<<<256, 256, 0, stream>>>(xbf, WT,               bq, nullptr, qbf, 2048, 0, qscale);
  gemm_bt_bias<<<256, 256, 0, stream>>>(xbf, WT + 1048576,     bk, kout, Kbf,   4096, 2048, 1.0f);
  gemm_bt_bias<<<256, 256, 0, stream>>>(xbf, WT + 2 * 1048576, bv, vout, nullptr, 4096, 2048, 1.0f);
  transpose_v_kernel<<<2048, 256, 0, stream>>>(vout, VTb);
  attn_kernel<<<2048, 256, 0, stream>>>(qbf, Kbf, VTb, maskW, pctx, mlp);
  combine_kernel<<<1024, 256, 0, stream>>>(pctx, mlp, ctxb);
  gemm_bt_bias<<<256, 256, 0, stream>>>(ctxb, WT + 3 * 1048576, bo, outf, nullptr, 2048, 0, 1.0f);
}